// Round 10
// baseline (195.391 us; speedup 1.0000x reference)
//
#include <hip/hip_runtime.h>

#define TT   256    // timesteps
#define FF   23     // lab features
#define HH   100    // hidden
#define NTHR 896    // 14 waves: 7 A-waves + 7 B-waves (split-K pairs)
#define NWG  256    // 4 rows per wg -> one wg per CU

typedef unsigned int  u32;
typedef unsigned short u16;
typedef __attribute__((ext_vector_type(8))) short short8;  // 8 bf16 in 4 VGPRs
typedef __attribute__((ext_vector_type(4))) float f32x4;

__device__ __forceinline__ u16 f2bf(float f){           // RTNE f32->bf16
  u32 u = __float_as_uint(f);
  u += 0x7fffu + ((u >> 16) & 1u);
  return (u16)(u >> 16);
}
__device__ __forceinline__ float fsig(float x){
  return __builtin_amdgcn_rcpf(1.0f + __expf(-x));
}
__device__ __forceinline__ float ftanh(float x){
  return 1.0f - 2.0f * __builtin_amdgcn_rcpf(__expf(2.0f * x) + 1.0f);
}

// Split-K pairs: waveA = w (0..6), waveB = w+7, both own columns j = w*16+nl.
//  waveA: xa(x feats + h-fold 23-26 + c-fold 27-30 + 1.0@k31) , h k0-31,
//         c k0-63  -> 11 MFMA  (biases ride k31 of wx/wdx)
//  waveB: h k32-95, c k64-95   -> 9 MFMA -> writes 5 f32 partials
//  mid-step barrier; waveA sums partials, pointwise, writes h/c + folds;
//  end-step barrier.  MFMA/CU/step unchanged (140) but 14 waves hide
//  ds_read latency + MFMA dep stalls.  A/B share acc/frag/weight registers
//  (disjoint roles) to keep VGPR <= 128 so all 14 waves are resident.
//
// LDS: sX[t][r*32+k] (static x + per-step folds), sHC[buf][h|c][kf*128+r*32+k]
// (k<96), sPart[5][4][112] f32 partials, sDec, sHF.  ~84 KB -> 1 wg/CU.

__global__ __launch_bounds__(NTHR) void tlstm11(
    const float* __restrict__ x_lab,  const float* __restrict__ t_lab,
    const float* __restrict__ x_state,const float* __restrict__ W_x,
    const float* __restrict__ W_h,    const float* __restrict__ b_lstm,
    const float* __restrict__ W_d,    const float* __restrict__ b_d,
    const float* __restrict__ W_state,const float* __restrict__ b_state,
    const float* __restrict__ W_fc,   const float* __restrict__ b_fc,
    float* __restrict__ out)
{
  __shared__ __align__(16) u16  sX[TT][128];     // 64 KB
  __shared__ __align__(16) u16  sHC[2][2][384];  // [buf][h=0/c=1][kf*128+r*32+k]
  __shared__ __align__(16) float sPart[5 * 448]; // [g|d][q4][112 cols]
  __shared__ __align__(16) float sDec[TT][4];    // dec(t,r) - 1
  __shared__ __align__(16) float sHF[4][128];

  const int tid  = threadIdx.x;
  const int lane = tid & 63;
  const int w    = tid >> 6;        // wave 0..13
  const bool isA = (w < 7);
  const int wp   = isA ? w : (w - 7);
  const int nl   = lane & 15;
  const int q4   = lane >> 4;
  const int b0   = blockIdx.x * 4;
  const int j    = wp * 16 + nl;    // hidden column (<=111; real <100)
  const bool jr  = (j < HH);

  // ---- zero h/c buffers ----
  for (int i = tid; i < 2*2*384/2; i += NTHR) ((u32*)sHC)[i] = 0u;

  // ---- stage x frags for all t (features + zero folds + 1.0 at k31) ----
  for (int e = tid; e < TT*128; e += NTHR) {
    int t = e >> 7, inner = e & 127, r = inner >> 5, k = inner & 31;
    float v = 0.f;
    if (k < FF)       v = x_lab[((b0 + r)*TT + t)*FF + k];
    else if (k == 31) v = 1.0f;
    sX[t][inner] = f2bf(v);
  }
  // ---- decay-minus-one table ----
  for (int e = tid; e < TT*4; e += NTHR) {
    int t = e >> 2, r = e & 3;
    sDec[t][r] = 1.0f / logf(2.718281828459045f + t_lab[(b0 + r)*TT + t]) - 1.0f;
  }

  // ---- role-dependent persistent weight fragments (shared registers) ----
  // A: wt[0-3]=wx[g], wt[4]=wdx, wt[5]=wd(k0-31), wt[6]=wd(k32-63), wt[7-10]=wh[g](k0-31)
  // B: wt[0-3]=wh[g](k32-63), wt[5]=wd(k64-95), wt[7-10]=wh[g](k64-95)
  short8 wt[11];
#pragma unroll
  for (int i = 0; i < 11; ++i) wt[i] = short8{0,0,0,0,0,0,0,0};
  if (jr) {
    if (isA) {
#pragma unroll
      for (int g = 0; g < 4; ++g) {
        short8 v;
#pragma unroll
        for (int i = 0; i < 8; ++i) {
          int k = q4*8 + i;
          float x = 0.f;
          if (k < FF)                 x = W_x[k*400 + g*HH + j];
          else if (k >= 23 && k < 27) x = W_h[(96 + (k-23))*400 + g*HH + j];
          else if (k == 31)           x = b_lstm[g*HH + j];
          v[i] = (short)f2bf(x);
        }
        wt[g] = v;
      }
      {
        short8 v;
#pragma unroll
        for (int i = 0; i < 8; ++i) {
          int k = q4*8 + i;
          float x = 0.f;
          if (k >= 27 && k < 31) x = W_d[(96 + (k-27))*HH + j];
          else if (k == 31)      x = b_d[j];
          v[i] = (short)f2bf(x);
        }
        wt[4] = v;
      }
#pragma unroll
      for (int kf = 0; kf < 2; ++kf) {
        short8 v;
#pragma unroll
        for (int i = 0; i < 8; ++i) v[i] = (short)f2bf(W_d[(kf*32 + q4*8 + i)*HH + j]);
        wt[5 + kf] = v;
      }
#pragma unroll
      for (int g = 0; g < 4; ++g) {
        short8 v;
#pragma unroll
        for (int i = 0; i < 8; ++i) v[i] = (short)f2bf(W_h[(q4*8 + i)*400 + g*HH + j]);
        wt[7 + g] = v;
      }
    } else {
#pragma unroll
      for (int g = 0; g < 4; ++g) {
        short8 v, u;
#pragma unroll
        for (int i = 0; i < 8; ++i) {
          v[i] = (short)f2bf(W_h[(32 + q4*8 + i)*400 + g*HH + j]);
          u[i] = (short)f2bf(W_h[(64 + q4*8 + i)*400 + g*HH + j]);
        }
        wt[g] = v; wt[7 + g] = u;
      }
      {
        short8 v;
#pragma unroll
        for (int i = 0; i < 8; ++i) v[i] = (short)f2bf(W_d[(64 + q4*8 + i)*HH + j]);
        wt[5] = v;
      }
    }
  }

  __syncthreads();

  const int  rbase = (nl >> 2)*32 + q4*8;      // broadcast within nl-groups
  const int  widx  = (j >> 5)*128 + q4*32 + (j & 31);  // valid for j<96
  const int  pidx  = q4*112 + j;               // partials slot
  const bool wbuf  = (wp < 6);
  const bool wfold = (wp == 6) && (nl < 4);    // j in 96..99 -> x-frag fold

  float cm = 0.f, hl = 0.f;
  const f32x4 zv = {0.f, 0.f, 0.f, 0.f};
  float* sP = sPart;

#define MFMA16(a,b,c) __builtin_amdgcn_mfma_f32_16x16x32_bf16(a, b, c, 0, 0, 0)

#define STEP_BODY(T, PC, PN)                                                  \
  {                                                                           \
    const u16* hb = sHC[PC][0];                                               \
    const u16* cb = sHC[PC][1];                                               \
    u16* hn = sHC[PN][0];                                                     \
    u16* cn = sHC[PN][1];                                                     \
    f32x4 acP0, acP1, acP2, acP3, acD0, acD1;                                 \
    if (isA) {                                                                \
      short8 f0 = *(const short8*)(sX[T] + rbase);   /* xa            */      \
      short8 f1 = *(const short8*)(cb +       rbase);/* c k0-31       */      \
      short8 f2 = *(const short8*)(cb + 128 + rbase);/* c k32-63      */      \
      short8 f3 = *(const short8*)(hb +       rbase);/* h k0-31       */      \
      acD0 = MFMA16(f0, wt[4], zv);                                           \
      acP0 = MFMA16(f0, wt[0], zv);                                           \
      acP1 = MFMA16(f0, wt[1], zv);                                           \
      acP2 = MFMA16(f0, wt[2], zv);                                           \
      acP3 = MFMA16(f0, wt[3], zv);                                           \
      acD0 = MFMA16(f1, wt[5], acD0);                                         \
      acD1 = MFMA16(f2, wt[6], zv);                                           \
      acP0 = MFMA16(f3, wt[7],  acP0);                                        \
      acP1 = MFMA16(f3, wt[8],  acP1);                                        \
      acP2 = MFMA16(f3, wt[9],  acP2);                                        \
      acP3 = MFMA16(f3, wt[10], acP3);                                        \
    } else {                                                                  \
      short8 f1 = *(const short8*)(hb + 128 + rbase);/* h k32-63      */      \
      short8 f2 = *(const short8*)(hb + 256 + rbase);/* h k64-95      */      \
      short8 f3 = *(const short8*)(cb + 256 + rbase);/* c k64-95      */      \
      acP0 = MFMA16(f1, wt[0], zv);                                           \
      acP1 = MFMA16(f1, wt[1], zv);                                           \
      acP2 = MFMA16(f1, wt[2], zv);                                           \
      acP3 = MFMA16(f1, wt[3], zv);                                           \
      acD0 = MFMA16(f3, wt[5], zv);                                           \
      acP0 = MFMA16(f2, wt[7],  acP0);                                        \
      acP1 = MFMA16(f2, wt[8],  acP1);                                        \
      acP2 = MFMA16(f2, wt[9],  acP2);                                        \
      acP3 = MFMA16(f2, wt[10], acP3);                                        \
      sP[pidx         ] = acP0[0];                                            \
      sP[pidx +  448  ] = acP1[0];                                            \
      sP[pidx +  896  ] = acP2[0];                                            \
      sP[pidx + 1344  ] = acP3[0];                                            \
      sP[pidx + 1792  ] = acD0[0];                                            \
    }                                                                         \
    __syncthreads();    /* partials + prev-state reads complete */            \
    if (isA) {                                                                \
      float decm1 = sDec[T][q4];                                              \
      float ds = acD0[0] + acD1[0] + sP[pidx + 1792];                         \
      float cs   = ftanh(ds);                                                 \
      float cadj = __builtin_fmaf(cs, decm1, cm);                             \
      float ig = fsig (acP0[0] + sP[pidx        ]);                           \
      float fg = fsig (acP1[0] + sP[pidx +  448 ]);                           \
      float gg = ftanh(acP2[0] + sP[pidx +  896 ]);                           \
      float og = fsig (acP3[0] + sP[pidx + 1344 ]);                           \
      float cnv = fg*cadj + ig*gg;  cm = cnv;                                 \
      float hv  = og*ftanh(cnv);    hl = hv;                                  \
      u32 pk;                                                                 \
      asm("v_cvt_pk_bf16_f32 %0, %1, %2" : "=v"(pk) : "v"(hv), "v"(cnv));     \
      if (wbuf) {                                                             \
        hn[widx] = (u16)pk;                                                   \
        cn[widx] = (u16)(pk >> 16);                                           \
      } else if (wfold && (T) + 1 < TT) {                                     \
        sX[(T)+1][q4*32 + 23 + nl] = (u16)pk;                                 \
        sX[(T)+1][q4*32 + 27 + nl] = (u16)(pk >> 16);                         \
      }                                                                       \
    }                                                                         \
    __syncthreads();    /* new state visible */                               \
  }

  for (int t = 0; t < TT; t += 2) {
    STEP_BODY(t,     0, 1)
    STEP_BODY(t + 1, 1, 0)
  }
#undef STEP_BODY
#undef MFMA16

  // ---- epilogue ----
  if (isA && jr) sHF[q4][j] = hl;
  __syncthreads();

  if (tid < 4) {
    const int bg = b0 + tid;
    float y0 = b_fc[0], y1 = b_fc[1];
    for (int k = 0; k < HH; ++k) {
      float hv = sHF[tid][k];
      y0 += hv * W_fc[2*k];
      y1 += hv * W_fc[2*k + 1];
    }
#pragma unroll
    for (int k = 0; k < 20; ++k) {
      float a = b_state[k];
#pragma unroll
      for (int s = 0; s < 6; ++s) a += x_state[bg*6 + s] * W_state[s*20 + k];
      y0 += a * W_fc[2*(HH + k)];
      y1 += a * W_fc[2*(HH + k) + 1];
    }
    float m = fmaxf(y0, y1);
    float e0 = __expf(y0 - m), e1 = __expf(y1 - m);
    float inv = 1.0f / (e0 + e1);
    out[bg*2 + 0] = e0 * inv;
    out[bg*2 + 1] = e1 * inv;
  }
}

extern "C" void kernel_launch(void* const* d_in, const int* in_sizes, int n_in,
                              void* d_out, int out_size, void* d_ws, size_t ws_size,
                              hipStream_t stream) {
  const float* x_lab   = (const float*)d_in[0];
  const float* t_lab   = (const float*)d_in[1];
  const float* x_state = (const float*)d_in[2];
  const float* W_x     = (const float*)d_in[3];
  const float* W_h     = (const float*)d_in[4];
  const float* b_lstm  = (const float*)d_in[5];
  const float* W_d     = (const float*)d_in[6];
  const float* b_d     = (const float*)d_in[7];
  const float* W_state = (const float*)d_in[8];
  const float* b_state = (const float*)d_in[9];
  const float* W_fc    = (const float*)d_in[10];
  const float* b_fc    = (const float*)d_in[11];
  float* outp = (float*)d_out;

  hipLaunchKernelGGL(tlstm11, dim3(NWG), dim3(NTHR), 0, stream,
                     x_lab, t_lab, x_state, W_x, W_h, b_lstm, W_d, b_d,
                     W_state, b_state, W_fc, b_fc, outp);
}

// Round 11
// 176.225 us; speedup vs baseline: 1.1088x; 1.1088x over previous
//
#include <hip/hip_runtime.h>

#define TT   256    // timesteps
#define FF   23     // lab features
#define HH   100    // hidden
#define NTHR 448    // 7 waves
#define NWG  256    // 4 rows per wg -> one wg per CU

typedef unsigned int  u32;
typedef unsigned short u16;
typedef __attribute__((ext_vector_type(8))) short short8;  // 8 bf16 in 4 VGPRs
typedef __attribute__((ext_vector_type(4))) float f32x4;

__device__ __forceinline__ u16 f2bf(float f){           // RTNE f32->bf16
  u32 u = __float_as_uint(f);
  u += 0x7fffu + ((u >> 16) & 1u);
  return (u16)(u >> 16);
}
__device__ __forceinline__ float fsig(float x){
  return __builtin_amdgcn_rcpf(1.0f + __expf(-x));
}
__device__ __forceinline__ float ftanh(float x){
  return 1.0f - 2.0f * __builtin_amdgcn_rcpf(__expf(2.0f * x) + 1.0f);
}

// One wg/CU, 4 batch rows in ONE M=16 tile-set (rows at tile-rows 4b ->
// C/D elem 0 of lane (q4,nl) = (batch row q4, col j)). 7 waves x 16 cols.
//
// A-frag reads are UNCONDITIONAL: lane (q4,nl) reads (nl>>2)*32 + q4*8 --
// lanes within an nl-group of 4 hit the same address (broadcast, free).
// Tile rows nl%4!=0 receive duplicated batch-row data -> garbage in C/D
// elems 1..3, which are never consumed. No exec-mask branch, no zeroing.
//
// LDS (bf16):
//  sX[t][r*32+k]: k 0-22 x features, 23-26 h[96..99] fold, 27-30 c[96..99]
//                 fold, 31 = 1.0 (biases sit in weight frags at k31).
//  sHC[buf][h|c][kf*128 + r*32 + k]: j<96 exactly (96 = 3 frags x 32).
// Issue order per step: xa read -> 5 xa-MFMAs (d1 + 4 gate-x) -> 3 ca-MFMAs
// (d done by #8) -> cs/cadj on VALU overlapping the 12 gate-h MFMAs.
//
// Structural plateau (measured R5/R6/R7/R10): the 4 rows must share one
// M=16 tile (else MFMA duplicates) -> one full-wg barrier per step (h/c
// all-to-all) -> lockstep waves. Step = barrier + ds_read latency + MFMA
// phase + transcendental tail; all de-alignment mechanisms measured worse.

__global__ __launch_bounds__(NTHR, 2) void tlstm10(
    const float* __restrict__ x_lab,  const float* __restrict__ t_lab,
    const float* __restrict__ x_state,const float* __restrict__ W_x,
    const float* __restrict__ W_h,    const float* __restrict__ b_lstm,
    const float* __restrict__ W_d,    const float* __restrict__ b_d,
    const float* __restrict__ W_state,const float* __restrict__ b_state,
    const float* __restrict__ W_fc,   const float* __restrict__ b_fc,
    float* __restrict__ out)
{
  __shared__ __align__(16) u16  sX[TT][128];    // 64 KB
  __shared__ __align__(16) u16  sHC[2][2][384]; // [buf][h=0/c=1][kf*128+r*32+k]
  __shared__ __align__(16) float sDec[TT][4];   // dec(t,r) - 1
  __shared__ __align__(16) float sHF[4][128];

  const int tid  = threadIdx.x;
  const int lane = tid & 63;
  const int w    = tid >> 6;        // wave 0..6
  const int nl   = lane & 15;
  const int q4   = lane >> 4;
  const int b0   = blockIdx.x * 4;
  const int j    = w * 16 + nl;     // hidden column (<=111; real <100)
  const bool jr  = (j < HH);

  // ---- zero h/c buffers ----
  for (int i = tid; i < 2*2*384/2; i += NTHR) ((u32*)sHC)[i] = 0u;

  // ---- stage x frags for all t (features + zero folds + 1.0 at k31) ----
  for (int e = tid; e < TT*128; e += NTHR) {
    int t = e >> 7, inner = e & 127, r = inner >> 5, k = inner & 31;
    float v = 0.f;
    if (k < FF)       v = x_lab[((b0 + r)*TT + t)*FF + k];
    else if (k == 31) v = 1.0f;
    sX[t][inner] = f2bf(v);
  }
  // ---- decay-minus-one table ----
  for (int e = tid; e < TT*4; e += NTHR) {
    int t = e >> 2, r = e & 3;
    sDec[t][r] = 1.0f / logf(2.718281828459045f + t_lab[(b0 + r)*TT + t]) - 1.0f;
  }

  // ---- persistent weight fragments (B-operand: col=nl -> j, k=kf*32+q4*8+i) ----
  short8 wh[4][3], wd[3], wdx, wx[4];
#pragma unroll
  for (int g = 0; g < 4; ++g)
#pragma unroll
    for (int kf = 0; kf < 3; ++kf) {
      short8 v;
#pragma unroll
      for (int i = 0; i < 8; ++i) {
        int k = kf*32 + q4*8 + i;                 // k <= 95: always real
        v[i] = (short)(jr ? f2bf(W_h[k*400 + g*HH + j]) : 0);
      }
      wh[g][kf] = v;
    }
#pragma unroll
  for (int kf = 0; kf < 3; ++kf) {
    short8 v;
#pragma unroll
    for (int i = 0; i < 8; ++i) {
      int k = kf*32 + q4*8 + i;
      v[i] = (short)(jr ? f2bf(W_d[k*HH + j]) : 0);
    }
    wd[kf] = v;
  }
  { // x-frag-matched d-weights: c-fold rows 27-30 + b_d at k31
    short8 v;
#pragma unroll
    for (int i = 0; i < 8; ++i) {
      int k = q4*8 + i;
      float x = 0.f;
      if (jr) {
        if (k >= 27 && k < 31) x = W_d[(96 + (k-27))*HH + j];
        else if (k == 31)      x = b_d[j];
      }
      v[i] = (short)f2bf(x);
    }
    wdx = v;
  }
#pragma unroll
  for (int g = 0; g < 4; ++g) { // x-weights: features + h-fold 23-26 + bias k31
    short8 v;
#pragma unroll
    for (int i = 0; i < 8; ++i) {
      int k = q4*8 + i;
      float x = 0.f;
      if (jr) {
        if (k < FF)                 x = W_x[k*400 + g*HH + j];
        else if (k >= 23 && k < 27) x = W_h[(96 + (k-23))*400 + g*HH + j];
        else if (k == 31)           x = b_lstm[g*HH + j];
      }
      v[i] = (short)f2bf(x);
    }
    wx[g] = v;
  }

  __syncthreads();

  const int  rbase = (nl >> 2)*32 + q4*8;      // broadcast within nl-groups
  const int  widx  = (j >> 5)*128 + q4*32 + (j & 31);  // valid for j<96
  const bool wbuf  = (w < 6);
  const bool wfold = (w == 6) && (nl < 4);     // j in 96..99 -> x-frag fold

  float cm = 0.f, hl = 0.f;
  const f32x4 zv = {0.f, 0.f, 0.f, 0.f};

#define MFMA16(a,b,c) __builtin_amdgcn_mfma_f32_16x16x32_bf16(a, b, c, 0, 0, 0)

#define STEP_BODY(T, PC, PN)                                                  \
  {                                                                           \
    const u16* hb = sHC[PC][0];                                               \
    const u16* cb = sHC[PC][1];                                               \
    u16* hn = sHC[PN][0];                                                     \
    u16* cn = sHC[PN][1];                                                     \
    /* reads in consumption order: xa first so its MFMAs start early */       \
    short8 xa  = *(const short8*)(sX[T] + rbase);                             \
    short8 ca0 = *(const short8*)(cb +       rbase);                          \
    short8 ca1 = *(const short8*)(cb + 128 + rbase);                          \
    short8 ca2 = *(const short8*)(cb + 256 + rbase);                          \
    short8 ha0 = *(const short8*)(hb +       rbase);                          \
    short8 ha1 = *(const short8*)(hb + 128 + rbase);                          \
    short8 ha2 = *(const short8*)(hb + 256 + rbase);                          \
    float decm1 = sDec[T][q4];                                                \
    /* 5 xa-MFMAs behind the first read only */                               \
    f32x4 d1 = MFMA16(xa, wdx,   zv);                                         \
    f32x4 p0 = MFMA16(xa, wx[0], zv);                                         \
    f32x4 p1 = MFMA16(xa, wx[1], zv);                                         \
    f32x4 p2 = MFMA16(xa, wx[2], zv);                                         \
    f32x4 p3 = MFMA16(xa, wx[3], zv);                                         \
    /* d completes by MFMA #8 -> its pointwise head overlaps the gates */     \
    f32x4 d0 = MFMA16(ca0, wd[0], zv);                                        \
    d1 = MFMA16(ca1, wd[1], d1);                                              \
    d0 = MFMA16(ca2, wd[2], d0);                                              \
    float csum = d0[0] + d1[0];                                               \
    float cs   = ftanh(csum);                                                 \
    float cadj = __builtin_fmaf(cs, decm1, cm);                               \
    /* 12 gate-h MFMAs; cs/cadj VALU work hides under their issue */          \
    p0 = MFMA16(ha0, wh[0][0], p0); p1 = MFMA16(ha0, wh[1][0], p1);           \
    p2 = MFMA16(ha0, wh[2][0], p2); p3 = MFMA16(ha0, wh[3][0], p3);           \
    p0 = MFMA16(ha1, wh[0][1], p0); p1 = MFMA16(ha1, wh[1][1], p1);           \
    p2 = MFMA16(ha1, wh[2][1], p2); p3 = MFMA16(ha1, wh[3][1], p3);           \
    p0 = MFMA16(ha2, wh[0][2], p0); p1 = MFMA16(ha2, wh[1][2], p1);           \
    p2 = MFMA16(ha2, wh[2][2], p2); p3 = MFMA16(ha2, wh[3][2], p3);           \
    float ig = fsig (p0[0]);                                                  \
    float fg = fsig (p1[0]);                                                  \
    float gg = ftanh(p2[0]);                                                  \
    float og = fsig (p3[0]);                                                  \
    float cnv = fg*cadj + ig*gg;  cm = cnv;                                   \
    float hv  = og*ftanh(cnv);    hl = hv;                                    \
    u32 pk;                                                                   \
    asm("v_cvt_pk_bf16_f32 %0, %1, %2" : "=v"(pk) : "v"(hv), "v"(cnv));       \
    if (wbuf) {                                                               \
      hn[widx] = (u16)pk;                                                     \
      cn[widx] = (u16)(pk >> 16);                                             \
    } else if (wfold && (T) + 1 < TT) {                                       \
      sX[(T)+1][q4*32 + 23 + nl] = (u16)pk;                                   \
      sX[(T)+1][q4*32 + 27 + nl] = (u16)(pk >> 16);                           \
    }                                                                         \
    __syncthreads();                                                          \
  }

  for (int t = 0; t < TT; t += 2) {
    STEP_BODY(t,     0, 1)
    STEP_BODY(t + 1, 1, 0)
  }
#undef STEP_BODY
#undef MFMA16

  // ---- epilogue ----
  if (jr) sHF[q4][j] = hl;
  __syncthreads();

  if (tid < 4) {
    const int bg = b0 + tid;
    float y0 = b_fc[0], y1 = b_fc[1];
    for (int k = 0; k < HH; ++k) {
      float hv = sHF[tid][k];
      y0 += hv * W_fc[2*k];
      y1 += hv * W_fc[2*k + 1];
    }
#pragma unroll
    for (int k = 0; k < 20; ++k) {
      float a = b_state[k];
#pragma unroll
      for (int s = 0; s < 6; ++s) a += x_state[bg*6 + s] * W_state[s*20 + k];
      y0 += a * W_fc[2*(HH + k)];
      y1 += a * W_fc[2*(HH + k) + 1];
    }
    float m = fmaxf(y0, y1);
    float e0 = __expf(y0 - m), e1 = __expf(y1 - m);
    float inv = 1.0f / (e0 + e1);
    out[bg*2 + 0] = e0 * inv;
    out[bg*2 + 1] = e1 * inv;
  }
}

extern "C" void kernel_launch(void* const* d_in, const int* in_sizes, int n_in,
                              void* d_out, int out_size, void* d_ws, size_t ws_size,
                              hipStream_t stream) {
  const float* x_lab   = (const float*)d_in[0];
  const float* t_lab   = (const float*)d_in[1];
  const float* x_state = (const float*)d_in[2];
  const float* W_x     = (const float*)d_in[3];
  const float* W_h     = (const float*)d_in[4];
  const float* b_lstm  = (const float*)d_in[5];
  const float* W_d     = (const float*)d_in[6];
  const float* b_d     = (const float*)d_in[7];
  const float* W_state = (const float*)d_in[8];
  const float* b_state = (const float*)d_in[9];
  const float* W_fc    = (const float*)d_in[10];
  const float* b_fc    = (const float*)d_in[11];
  float* outp = (float*)d_out;

  hipLaunchKernelGGL(tlstm10, dim3(NWG), dim3(NTHR), 0, stream,
                     x_lab, t_lab, x_state, W_x, W_h, b_lstm, W_d, b_d,
                     W_state, b_state, W_fc, b_fc, outp);
}